// Round 8
// baseline (16375.797 us; speedup 1.0000x reference)
//
#include <hip/hip_runtime.h>
#include <hip/hip_bf16.h>
#include <cstdint>
#include <cstddef>

// ---------------------------------------------------------------------------
// EnrichAttention: B=32, L1=L2=512, H=A=256, 3H=768, 2H=512
// R14: multi-block GRU (gru_mc): each batch split across 8 blocks (256 blocks
//      total, all CUs). Block g owns elements [32g,32g+32): computes its own
//      r/z/n rows (48 MFMAs/step, 6x less per CU) + gates; h-slices exchanged
//      per step via global double buffer hg[2][32][256] with device-scope
//      release/acquire on per-batch counters. Step-0 h-read skipped (h0=0).
//      cnt zeroed by gemm_xp (stream-ordered just before gru).
//      Also fixes R13 latent race: a1db moved to base+8MB (was overlapped by
//      Msb's upper half during gemm_M).
// ---------------------------------------------------------------------------

typedef short s8v __attribute__((ext_vector_type(8)));      // 8 bf16 (4 VGPRs)
typedef float f4v __attribute__((ext_vector_type(4)));      // MFMA accumulator
typedef _Float16 h8v __attribute__((ext_vector_type(8)));   // 8 f16 (4 VGPRs)

#if __has_builtin(__builtin_amdgcn_sched_barrier)
#define SCHED_FENCE() __builtin_amdgcn_sched_barrier(0)
#else
#define SCHED_FENCE() asm volatile("" ::: "memory")
#endif

// Workgroup barrier waiting only on LDS (lgkmcnt).
__device__ __forceinline__ void bar_lds() {
    asm volatile("s_waitcnt lgkmcnt(0)\n\ts_barrier" ::: "memory");
}

__device__ __forceinline__ float fast_exp(float x) {
#if __has_builtin(__builtin_amdgcn_exp2f)
    return __builtin_amdgcn_exp2f(x * 1.44269504f);
#else
    return __expf(x);
#endif
}
__device__ __forceinline__ float fast_rcp(float x) {
#if __has_builtin(__builtin_amdgcn_rcpf)
    return __builtin_amdgcn_rcpf(x);
#else
    return 1.f / x;
#endif
}
__device__ __forceinline__ float fast_sig(float x) { return fast_rcp(1.f + fast_exp(-x)); }
__device__ __forceinline__ float fast_tanh(float x) {
    return 1.f - 2.f * fast_rcp(1.f + fast_exp(2.f * x));
}

// ---------------------------------------------------------------------------
// MFMA bf16 NT GEMM: C[M,N] = A[M,K] * B[N,K]^T. (Verified in R5.)
// ---------------------------------------------------------------------------
__global__ __launch_bounds__(256) void gemm_bf16(
    const __hip_bfloat16* __restrict__ A, int lda, long long sA,
    const __hip_bfloat16* __restrict__ B, int ldb, long long sB,
    void* __restrict__ C, int ldc, long long sC,
    int K,
    const float* __restrict__ bias,
    const float* __restrict__ emul, int ldmul,
    int relu, int accum, int out_bf16)
{
    __shared__ short As[128][40];
    __shared__ short Bs[128][40];

    const int tid  = threadIdx.x;
    const int wave = tid >> 6, lane = tid & 63;
    const int quad = lane >> 4, l16 = lane & 15;
    const int wrow = (wave >> 1) * 64, wcol = (wave & 1) * 64;
    const int m0 = blockIdx.y * 128, n0 = blockIdx.x * 128;

    const short* Ab = (const short*)A + (size_t)blockIdx.z * sA;
    const short* Bb = (const short*)B + (size_t)blockIdx.z * sB;

    f4v acc[4][4];
#pragma unroll
    for (int i = 0; i < 4; ++i)
#pragma unroll
        for (int j = 0; j < 4; ++j) acc[i][j] = 0.f;

    const int r0 = tid >> 2,        s0 = (tid & 3) * 8;
    const int r1 = (tid + 256) >> 2, s1 = ((tid + 256) & 3) * 8;

    for (int k0 = 0; k0 < K; k0 += 32) {
        *(s8v*)&As[r0][s0] = *(const s8v*)(Ab + (size_t)(m0 + r0) * lda + k0 + s0);
        *(s8v*)&As[r1][s1] = *(const s8v*)(Ab + (size_t)(m0 + r1) * lda + k0 + s1);
        *(s8v*)&Bs[r0][s0] = *(const s8v*)(Bb + (size_t)(n0 + r0) * ldb + k0 + s0);
        *(s8v*)&Bs[r1][s1] = *(const s8v*)(Bb + (size_t)(n0 + r1) * ldb + k0 + s1);
        __syncthreads();

        s8v af[4], bf[4];
#pragma unroll
        for (int i = 0; i < 4; ++i)
            af[i] = *(const s8v*)&As[wrow + i * 16 + l16][quad * 8];
#pragma unroll
        for (int j = 0; j < 4; ++j)
            bf[j] = *(const s8v*)&Bs[wcol + j * 16 + l16][quad * 8];
#pragma unroll
        for (int i = 0; i < 4; ++i)
#pragma unroll
            for (int j = 0; j < 4; ++j)
                acc[i][j] = __builtin_amdgcn_mfma_f32_16x16x32_bf16(
                    af[i], bf[j], acc[i][j], 0, 0, 0);
        __syncthreads();
    }

    float* Cf = (float*)C + (size_t)blockIdx.z * sC;
    __hip_bfloat16* Cb = (__hip_bfloat16*)C + (size_t)blockIdx.z * sC;
#pragma unroll
    for (int i = 0; i < 4; ++i)
#pragma unroll
        for (int j = 0; j < 4; ++j)
#pragma unroll
            for (int r = 0; r < 4; ++r) {
                const int m = m0 + wrow + i * 16 + quad * 4 + r;
                const int n = n0 + wcol + j * 16 + l16;
                float v = acc[i][j][r];
                if (bias)  v += bias[n];
                if (accum) v += Cf[(size_t)m * ldc + n];
                if (emul)  v *= emul[(size_t)m * ldmul + n];
                if (relu)  v = fmaxf(v, 0.f);
                if (out_bf16) Cb[(size_t)m * ldc + n] = __float2bfloat16(v);
                else          Cf[(size_t)m * ldc + n] = v;
            }
}

// ---------------------------------------------------------------------------
// M GEMM + fused softmax numerator (verified R13):
//   E = bf16(exp((a1d@a2^T)*W)); S[b][n] += column sums (fp32 atomics).
// ---------------------------------------------------------------------------
__global__ __launch_bounds__(256) void gemm_M(
    const __hip_bfloat16* __restrict__ A,   // a1db [32][512][256]
    const __hip_bfloat16* __restrict__ B,   // a2b  [32][512][256]
    __hip_bfloat16* __restrict__ E,         // Msb  [32][512][512]
    const float* __restrict__ Wm,           // [512,512]
    float* __restrict__ S)                  // [32][512] (pre-zeroed)
{
    __shared__ short As[128][40];
    __shared__ short Bs[128][40];

    const int tid  = threadIdx.x;
    const int wave = tid >> 6, lane = tid & 63;
    const int quad = lane >> 4, l16 = lane & 15;
    const int wrow = (wave >> 1) * 64, wcol = (wave & 1) * 64;
    const int m0 = blockIdx.y * 128, n0 = blockIdx.x * 128;

    const short* Ab = (const short*)A + (size_t)blockIdx.z * 131072;
    const short* Bb = (const short*)B + (size_t)blockIdx.z * 131072;

    f4v acc[4][4];
#pragma unroll
    for (int i = 0; i < 4; ++i)
#pragma unroll
        for (int j = 0; j < 4; ++j) acc[i][j] = 0.f;

    const int r0 = tid >> 2,        s0 = (tid & 3) * 8;
    const int r1 = (tid + 256) >> 2, s1 = ((tid + 256) & 3) * 8;

    for (int k0 = 0; k0 < 256; k0 += 32) {
        *(s8v*)&As[r0][s0] = *(const s8v*)(Ab + (size_t)(m0 + r0) * 256 + k0 + s0);
        *(s8v*)&As[r1][s1] = *(const s8v*)(Ab + (size_t)(m0 + r1) * 256 + k0 + s1);
        *(s8v*)&Bs[r0][s0] = *(const s8v*)(Bb + (size_t)(n0 + r0) * 256 + k0 + s0);
        *(s8v*)&Bs[r1][s1] = *(const s8v*)(Bb + (size_t)(n0 + r1) * 256 + k0 + s1);
        __syncthreads();

        s8v af[4], bf[4];
#pragma unroll
        for (int i = 0; i < 4; ++i)
            af[i] = *(const s8v*)&As[wrow + i * 16 + l16][quad * 8];
#pragma unroll
        for (int j = 0; j < 4; ++j)
            bf[j] = *(const s8v*)&Bs[wcol + j * 16 + l16][quad * 8];
#pragma unroll
        for (int i = 0; i < 4; ++i)
#pragma unroll
            for (int j = 0; j < 4; ++j)
                acc[i][j] = __builtin_amdgcn_mfma_f32_16x16x32_bf16(
                    af[i], bf[j], acc[i][j], 0, 0, 0);
        __syncthreads();
    }

    __hip_bfloat16* Eb = E + (size_t)blockIdx.z * 262144;
    float* Sb = S + blockIdx.z * 512;
#pragma unroll
    for (int j = 0; j < 4; ++j) {
        const int n = n0 + wcol + j * 16 + l16;
        float colsum = 0.f;
#pragma unroll
        for (int i = 0; i < 4; ++i)
#pragma unroll
            for (int r = 0; r < 4; ++r) {
                const int m = m0 + wrow + i * 16 + quad * 4 + r;
                float v = acc[i][j][r] * Wm[(size_t)m * 512 + n];
                float e = __expf(v);
                colsum += e;
                Eb[(size_t)m * 512 + n] = __float2bfloat16(e);
            }
        atomicAdd(&Sb[n], colsum);
    }
}

// In-place softmax normalization: Msb[b][i][j] /= S[b][j]. 8 bf16/thread.
__global__ __launch_bounds__(256) void sm_scale(
    __hip_bfloat16* __restrict__ E, const float* __restrict__ S)
{
    const size_t t  = (size_t)blockIdx.x * 256 + threadIdx.x;
    const size_t e0 = t * 8;
    const int j0 = (int)(e0 & 511);
    const int b  = (int)(e0 >> 18);
    const float* Sb = S + b * 512 + j0;

    union { s8v v; __hip_bfloat16 h[8]; } u;
    u.v = *(const s8v*)(E + e0);
#pragma unroll
    for (int k = 0; k < 8; ++k)
        u.h[k] = __float2bfloat16(__bfloat162float(u.h[k]) / Sb[k]);
    *(s8v*)(E + e0) = u.v;
}

// ---------------------------------------------------------------------------
// Fused xp GEMM (verified R10) + zeroing of the GRU sync counters (cnt lives
// in the dead x2tb region; gemm_xp is the last kernel before gru_mc).
// ---------------------------------------------------------------------------
__global__ __launch_bounds__(256) void gemm_xp(
    const __hip_bfloat16* __restrict__ A1,   // x1b  [16384,256]
    const __hip_bfloat16* __restrict__ A2,   // ctxb [16384,256]
    const __hip_bfloat16* __restrict__ B,    // wihb [768,512]
    float* __restrict__ C,                   // xp   [16384,768]
    const float* __restrict__ bias,          // bih  [768]
    unsigned int* __restrict__ cnt)          // [32] GRU sync counters
{
    if (blockIdx.x == 0 && blockIdx.y == 0 && threadIdx.x < 32)
        cnt[threadIdx.x] = 0u;

    __shared__ short As[128][40];
    __shared__ short Bs[128][40];

    const int tid  = threadIdx.x;
    const int wave = tid >> 6, lane = tid & 63;
    const int quad = lane >> 4, l16 = lane & 15;
    const int wrow = (wave >> 1) * 64, wcol = (wave & 1) * 64;
    const int m0 = blockIdx.y * 128, n0 = blockIdx.x * 128;

    f4v acc[4][4];
#pragma unroll
    for (int i = 0; i < 4; ++i)
#pragma unroll
        for (int j = 0; j < 4; ++j) acc[i][j] = 0.f;

    const int r0 = tid >> 2,        s0 = (tid & 3) * 8;
    const int r1 = (tid + 256) >> 2, s1 = ((tid + 256) & 3) * 8;

    for (int k0 = 0; k0 < 512; k0 += 32) {
        const short* Ab = (const short*)(k0 < 256 ? A1 : A2);
        const int ka = k0 & 255;
        *(s8v*)&As[r0][s0] = *(const s8v*)(Ab + (size_t)(m0 + r0) * 256 + ka + s0);
        *(s8v*)&As[r1][s1] = *(const s8v*)(Ab + (size_t)(m0 + r1) * 256 + ka + s1);
        *(s8v*)&Bs[r0][s0] = *(const s8v*)((const short*)B + (size_t)(n0 + r0) * 512 + k0 + s0);
        *(s8v*)&Bs[r1][s1] = *(const s8v*)((const short*)B + (size_t)(n0 + r1) * 512 + k0 + s1);
        __syncthreads();

        s8v af[4], bf[4];
#pragma unroll
        for (int i = 0; i < 4; ++i)
            af[i] = *(const s8v*)&As[wrow + i * 16 + l16][quad * 8];
#pragma unroll
        for (int j = 0; j < 4; ++j)
            bf[j] = *(const s8v*)&Bs[wcol + j * 16 + l16][quad * 8];
#pragma unroll
        for (int i = 0; i < 4; ++i)
#pragma unroll
            for (int j = 0; j < 4; ++j)
                acc[i][j] = __builtin_amdgcn_mfma_f32_16x16x32_bf16(
                    af[i], bf[j], acc[i][j], 0, 0, 0);
        __syncthreads();
    }

#pragma unroll
    for (int i = 0; i < 4; ++i)
#pragma unroll
        for (int j = 0; j < 4; ++j)
#pragma unroll
            for (int r = 0; r < 4; ++r) {
                const int m = m0 + wrow + i * 16 + quad * 4 + r;
                const int n = n0 + wcol + j * 16 + l16;
                C[(size_t)m * 768 + n] = acc[i][j][r] + bias[n];
            }
}

// fp32 -> bf16 elementwise (n % 4 == 0)
__global__ __launch_bounds__(256) void f2b(
    const float* __restrict__ s, __hip_bfloat16* __restrict__ d, int n)
{
    const int i = (blockIdx.x * 256 + threadIdx.x) * 4;
    if (i < n) {
        float4 v = *(const float4*)(s + i);
        d[i + 0] = __float2bfloat16(v.x);
        d[i + 1] = __float2bfloat16(v.y);
        d[i + 2] = __float2bfloat16(v.z);
        d[i + 3] = __float2bfloat16(v.w);
    }
}

// w1 + w2 casts merged + softmax-sum buffer S zeroed (runs pre-M-GEMM).
__global__ __launch_bounds__(256) void f2bw(
    const float* __restrict__ w1, const float* __restrict__ w2,
    __hip_bfloat16* __restrict__ w1b, __hip_bfloat16* __restrict__ w2b,
    float* __restrict__ S)
{
    const int gid = blockIdx.x * 256 + threadIdx.x;
    if (gid < 4096)
        *(float4*)(S + gid * 4) = make_float4(0.f, 0.f, 0.f, 0.f);
    const int i = gid * 4;
    const float* s;
    __hip_bfloat16* d;
    if (i < 65536) { s = w1 + i;           d = w1b + i; }
    else           { s = w2 + (i - 65536); d = w2b + (i - 65536); }
    float4 v = *(const float4*)s;
    d[0] = __float2bfloat16(v.x);
    d[1] = __float2bfloat16(v.y);
    d[2] = __float2bfloat16(v.z);
    d[3] = __float2bfloat16(v.w);
}

// fp32 [Z][R][C] -> bf16 [Z][C][R] tiled transpose
__global__ __launch_bounds__(256) void tr_f2b(
    const float* __restrict__ src, __hip_bfloat16* __restrict__ dst,
    int R, int C, long long sS, long long sD)
{
    __shared__ float t[32][33];
    const int r0 = blockIdx.y * 32, c0 = blockIdx.x * 32;
    const int tx = threadIdx.x & 31, ty = threadIdx.x >> 5;
    const float* S = src + (size_t)blockIdx.z * sS;
    __hip_bfloat16* Dd = dst + (size_t)blockIdx.z * sD;
#pragma unroll
    for (int i = 0; i < 32; i += 8)
        t[ty + i][tx] = S[(size_t)(r0 + ty + i) * C + c0 + tx];
    __syncthreads();
#pragma unroll
    for (int i = 0; i < 32; i += 8)
        Dd[(size_t)(c0 + ty + i) * R + r0 + tx] = __float2bfloat16(t[tx][ty + i]);
}

// Fused: x2 fp32 [Z][R][C] -> x2b bf16 same layout AND x2tb bf16 [Z][C][R].
__global__ __launch_bounds__(256) void f2b_tr(
    const float* __restrict__ src, __hip_bfloat16* __restrict__ dcast,
    __hip_bfloat16* __restrict__ dtr,
    int R, int C, long long sS, long long sD)
{
    __shared__ float t[32][33];
    const int r0 = blockIdx.y * 32, c0 = blockIdx.x * 32;
    const int tx = threadIdx.x & 31, ty = threadIdx.x >> 5;
    const float* S = src + (size_t)blockIdx.z * sS;
    __hip_bfloat16* Dc = dcast + (size_t)blockIdx.z * sS;
    __hip_bfloat16* Dd = dtr + (size_t)blockIdx.z * sD;
#pragma unroll
    for (int i = 0; i < 32; i += 8) {
        const size_t idx = (size_t)(r0 + ty + i) * C + c0 + tx;
        float v = S[idx];
        t[ty + i][tx] = v;
        Dc[idx] = __float2bfloat16(v);
    }
    __syncthreads();
#pragma unroll
    for (int i = 0; i < 32; i += 8)
        Dd[(size_t)(c0 + ty + i) * R + r0 + tx] = __float2bfloat16(t[tx][ty + i]);
}

// ---------------------------------------------------------------------------
// gru_mc: multi-block GRU. Grid = 256 blocks x 384 threads (6 waves).
//   b = blockIdx>>3, g = blockIdx&7. Block (b,g) owns elements e in
//   [32g, 32g+32): computes rows {e}, {256+e}, {512+e} (6 16-row tiles, one
//   per wave; 8 MFMAs each) with weights in registers, gates on tid<32,
//   and publishes its 32-element h-slice (f16) to hg[(t+1)&1][b].
//   Per-step sync: store slice -> __threadfence (agent release) ->
//   atomicAdd(cnt[b]) -> tid0 spins (agent-acquire load, guard-capped) until
//   cnt[b] >= 8(t+1) -> __syncthreads. Step 0 skips the h read (h0 = 0), so
//   hg needs no pre-zero; cnt zeroed by gemm_xp (stream-ordered before).
//   All 256 blocks are co-resident (1 block/CU) -> spin cannot deadlock;
//   guard bails after ~4M polls to fail-visible instead of hanging.
//   Math identical to R13 GRU: f16 h, fp32 gates, full-K rows in-block.
// ---------------------------------------------------------------------------
__global__ __launch_bounds__(384, 2)
void gru_mc(
    const float* __restrict__ xproj,   // [32,512,768]
    const float* __restrict__ whh,     // [768,256]
    const float* __restrict__ bhh,     // [768]
    float* __restrict__ out,           // [32,512,256]
    _Float16* __restrict__ hg,         // [2][32][256]
    unsigned int* __restrict__ cnt)    // [32]
{
    const int b = blockIdx.x >> 3, g = blockIdx.x & 7;
    const int tid = threadIdx.x;
    const int wave = tid >> 6, lane = tid & 63;
    const int quad = lane >> 4, l16 = lane & 15;

    __shared__ __align__(16) float hpl[96];

    const int e0 = 32 * g;
    const int sec = wave >> 1;                           // 0=r, 1=z, 2=n
    const int rowb = sec * 256 + e0 + (wave & 1) * 16;   // tile's global row base

    // Weight A-fragments for this wave's 16-row tile: wreg[kk] =
    // whh[rowb+l16][kk*32 + quad*8 .. +7] as f16.
    h8v wreg[8];
    if (wave < 6) {
        const float* rp = whh + (size_t)(rowb + l16) * 256 + quad * 8;
#pragma unroll
        for (int kk = 0; kk < 8; ++kk) {
            float4 t0 = *(const float4*)(rp + kk * 32);
            float4 t1 = *(const float4*)(rp + kk * 32 + 4);
            h8v f;
            f[0] = (_Float16)t0.x; f[1] = (_Float16)t0.y;
            f[2] = (_Float16)t0.z; f[3] = (_Float16)t0.w;
            f[4] = (_Float16)t1.x; f[5] = (_Float16)t1.y;
            f[6] = (_Float16)t1.z; f[7] = (_Float16)t1.w;
            wreg[kk] = f;
        }
    }

    const float* xb = xproj + (size_t)b * 512 * 768;
    float*       ob = out   + (size_t)b * 512 * 256;

    float br = 0.f, bz = 0.f, bn = 0.f, xr = 0.f, xz = 0.f, xn = 0.f, hA = 0.f;
    if (tid < 32) {
        const int e = e0 + tid;
        br = bhh[e]; bz = bhh[256 + e]; bn = bhh[512 + e];
        xr = xb[e];  xz = xb[256 + e];  xn = xb[512 + e];
    }
    unsigned int* cb = cnt + b;

    for (int t = 0; t < 512; ++t) {
        // x(t+1) prefetch (in flight across the whole step)
        float nxr = 0.f, nxz = 0.f, nxn = 0.f;
        if (tid < 32) {
            const float* xpn = xb + (size_t)((t + 1) & 511) * 768 + e0 + tid;
            nxr = xpn[0]; nxz = xpn[256]; nxn = xpn[512];
        }

        // matvec slice: 8 MFMAs per wave, h fragments read from hg (L2/L3)
        if (wave < 6) {
            f4v acc;
            acc = 0.f;
            if (t > 0) {
                const _Float16* hc = hg + ((size_t)(t & 1) * 32 + b) * 256 + quad * 8;
#pragma unroll
                for (int kk = 0; kk < 8; ++kk) {
                    h8v bf = *(const h8v*)(hc + kk * 32);
                    acc = __builtin_amdgcn_mfma_f32_16x16x32_f16(
                        wreg[kk], bf, acc, 0, 0, 0);
                }
            }
            if (l16 == 0)   // D replicated across l16; rows = quad*4+rr
                *(f4v*)&hpl[wave * 16 + quad * 4] = acc;
        }
        bar_lds();

        // gates for this block's 32 elements (wave 0, lanes 0..31)
        if (tid < 32) {
            float r = fast_sig(xr + br + hpl[tid]);
            float z = fast_sig(xz + bz + hpl[32 + tid]);
            float n = fast_tanh(xn + r * (hpl[64 + tid] + bn));
            float h = (1.f - z) * n + z * hA;
            hA = h;
            hg[((size_t)((t + 1) & 1) * 32 + b) * 256 + e0 + tid] = (_Float16)h;
            xr = nxr; xz = nxz; xn = nxn;
        }

        // release: slice visible device-wide, then arrive
        __threadfence();
        if (tid == 0) {
            atomicAdd(cb, 1u);
            const unsigned int tgt = 8u * (unsigned int)(t + 1);
            int guard = 1 << 22;   // fail-visible instead of hanging
            while (__hip_atomic_load(cb, __ATOMIC_ACQUIRE,
                                     __HIP_MEMORY_SCOPE_AGENT) < tgt && --guard)
                __builtin_amdgcn_s_sleep(2);
        }
        __syncthreads();

        // out write off the critical path (overlaps next step)
        if (tid < 32)
            ob[(size_t)t * 256 + e0 + tid] = hA;
    }
}

extern "C" void kernel_launch(void* const* d_in, const int* in_sizes, int n_in,
                              void* d_out, int out_size, void* d_ws, size_t ws_size,
                              hipStream_t stream)
{
    (void)in_sizes; (void)n_in; (void)out_size; (void)ws_size;

    const float* x1  = (const float*)d_in[0];   // [32,512,256]
    const float* x2  = (const float*)d_in[1];   // [32,512,256]
    const float* w1  = (const float*)d_in[2];   // [256,256]
    const float* w2  = (const float*)d_in[3];   // [256,256]
    const float* Dm  = (const float*)d_in[4];   // [256,256]
    const float* Wm  = (const float*)d_in[5];   // [512,512]
    const float* wih = (const float*)d_in[6];   // [768,512]
    const float* whh = (const float*)d_in[7];   // [768,256]
    const float* bih = (const float*)d_in[8];   // [768]
    const float* bhh = (const float*)d_in[9];   // [768]
    float* out = (float*)d_out;

    // Workspace aliasing. Changes vs R13: a1db moved to +8MB (fixes the
    // gemm_M read/write overlap with Msb); hg/cnt live in the x2tb region
    // (dead after the ctx GEMM; cnt zeroed by gemm_xp each launch).
    char* base = (char*)d_ws;
    __hip_bfloat16* w1b  = (__hip_bfloat16*)(base + 0);
    __hip_bfloat16* w2b  = (__hip_bfloat16*)(base + 131072);
    __hip_bfloat16* Dtb  = (__hip_bfloat16*)(base + 262144);
    float*          Ssum = (float*)(base + 1048576);        // [32*512] fp32
    float*          xp   = (float*)(base + 0);
    __hip_bfloat16* a1db = (__hip_bfloat16*)(base + 8388608);
    __hip_bfloat16* a1b  = (__hip_bfloat16*)(base + 33554432);
    __hip_bfloat16* Msb  = (__hip_bfloat16*)(base + 33554432);
    __hip_bfloat16* x1b  = (__hip_bfloat16*)(base + 50331648);
    __hip_bfloat16* x2b  = (__hip_bfloat16*)(base + 58720256);
    __hip_bfloat16* ctxb = (__hip_bfloat16*)(base + 58720256);
    __hip_bfloat16* x2tb = (__hip_bfloat16*)(base + 67108864);
    _Float16*       hg   = (_Float16*)(base + 67108864);    // overlays x2tb (dead)
    unsigned int*   hcnt = (unsigned int*)(base + 67174400);
    __hip_bfloat16* a2b  = (__hip_bfloat16*)(base + 75497472);
    __hip_bfloat16* wihb = (__hip_bfloat16*)(base + 75497472);

    dim3 blk(256);

    f2b<<<dim3(4096), blk, 0, stream>>>(x1, x1b, 4194304);
    f2b_tr<<<dim3(8, 16, 32), blk, 0, stream>>>(x2, x2b, x2tb, 512, 256, 131072, 131072);
    f2bw<<<dim3(128), blk, 0, stream>>>(w1, w2, w1b, w2b, Ssum);
    tr_f2b<<<dim3(8, 8, 1), blk, 0, stream>>>(Dm, Dtb, 256, 256, 0, 0);

    gemm_bf16<<<dim3(2, 128, 1), blk, 0, stream>>>(
        x1b, 256, 0, w1b, 256, 0, a1b, 256, 0, 256,
        nullptr, nullptr, 0, 1, 0, 1);
    gemm_bf16<<<dim3(2, 128, 1), blk, 0, stream>>>(
        x2b, 256, 0, w2b, 256, 0, a2b, 256, 0, 256,
        nullptr, nullptr, 0, 1, 0, 1);
    gemm_bf16<<<dim3(2, 128, 1), blk, 0, stream>>>(
        a1b, 256, 0, Dtb, 256, 0, a1db, 256, 0, 256,
        nullptr, nullptr, 0, 0, 0, 1);
    // M GEMM with fused exp + column-sum atomics
    gemm_M<<<dim3(4, 4, 32), blk, 0, stream>>>(a1db, a2b, Msb, Wm, Ssum);
    // wihb aliases a2b: cast only after gemm_M consumed a2b.
    f2b<<<dim3(384), blk, 0, stream>>>(wih, wihb, 393216);
    // softmax denominator: Msb /= S (in place)
    sm_scale<<<dim3(4096), blk, 0, stream>>>(Msb, Ssum);
    gemm_bf16<<<dim3(2, 4, 32), blk, 0, stream>>>(
        Msb, 512, 262144, x2tb, 512, 131072, ctxb, 256, 131072, 512,
        nullptr, nullptr, 0, 0, 0, 1);
    // Fused xp GEMM; also zeroes the GRU sync counters (x2tb now dead)
    gemm_xp<<<dim3(6, 128, 1), blk, 0, stream>>>(x1b, ctxb, wihb, xp, bih, hcnt);
    // Multi-block GRU: 8 blocks per batch, all 256 CUs
    gru_mc<<<dim3(256), dim3(384), 0, stream>>>(xp, whh, bhh, out, hg, hcnt);
}

// Round 9
// 878.081 us; speedup vs baseline: 18.6495x; 18.6495x over previous
//
#include <hip/hip_runtime.h>
#include <hip/hip_bf16.h>
#include <cstdint>
#include <cstddef>

// ---------------------------------------------------------------------------
// EnrichAttention: B=32, L1=L2=512, H=A=256, 3H=768, 2H=512
// R15: REVERT of R14's multi-block GRU (16.2ms: per-step cross-block fence+
//      atomic = ~76k cyc/step on 8 non-coherent XCD L2s — recurrences must
//      stay intra-block). GRU back to the verified R11/R13 kernel (658us).
//      Kept from R14: a1db at base+8MB (fixes gemm_M read/write overlap).
//      New (small): softmax denominator folded into x2tb (K-dim scaling,
//      algebraically identical, 1/4 the traffic of scaling Msb).
// ---------------------------------------------------------------------------

typedef short s8v __attribute__((ext_vector_type(8)));      // 8 bf16 (4 VGPRs)
typedef float f4v __attribute__((ext_vector_type(4)));      // MFMA accumulator
typedef _Float16 h8v __attribute__((ext_vector_type(8)));   // 8 f16 (4 VGPRs)

#if __has_builtin(__builtin_amdgcn_sched_barrier)
#define SCHED_FENCE() __builtin_amdgcn_sched_barrier(0)
#else
#define SCHED_FENCE() asm volatile("" ::: "memory")
#endif

// Workgroup barrier waiting only on LDS (lgkmcnt). Only hhf/hp (LDS) carry
// cross-thread deps in the GRU loop; global loads stay in flight across it.
__device__ __forceinline__ void bar_lds() {
    asm volatile("s_waitcnt lgkmcnt(0)\n\ts_barrier" ::: "memory");
}

__device__ __forceinline__ float fast_exp(float x) {
#if __has_builtin(__builtin_amdgcn_exp2f)
    return __builtin_amdgcn_exp2f(x * 1.44269504f);
#else
    return __expf(x);
#endif
}
__device__ __forceinline__ float fast_rcp(float x) {
#if __has_builtin(__builtin_amdgcn_rcpf)
    return __builtin_amdgcn_rcpf(x);
#else
    return 1.f / x;
#endif
}
__device__ __forceinline__ float fast_sig(float x) { return fast_rcp(1.f + fast_exp(-x)); }
__device__ __forceinline__ float fast_tanh(float x) {
    return 1.f - 2.f * fast_rcp(1.f + fast_exp(2.f * x));
}

// ---------------------------------------------------------------------------
// MFMA bf16 NT GEMM: C[M,N] = A[M,K] * B[N,K]^T. (Verified in R5.)
// ---------------------------------------------------------------------------
__global__ __launch_bounds__(256) void gemm_bf16(
    const __hip_bfloat16* __restrict__ A, int lda, long long sA,
    const __hip_bfloat16* __restrict__ B, int ldb, long long sB,
    void* __restrict__ C, int ldc, long long sC,
    int K,
    const float* __restrict__ bias,
    const float* __restrict__ emul, int ldmul,
    int relu, int accum, int out_bf16)
{
    __shared__ short As[128][40];
    __shared__ short Bs[128][40];

    const int tid  = threadIdx.x;
    const int wave = tid >> 6, lane = tid & 63;
    const int quad = lane >> 4, l16 = lane & 15;
    const int wrow = (wave >> 1) * 64, wcol = (wave & 1) * 64;
    const int m0 = blockIdx.y * 128, n0 = blockIdx.x * 128;

    const short* Ab = (const short*)A + (size_t)blockIdx.z * sA;
    const short* Bb = (const short*)B + (size_t)blockIdx.z * sB;

    f4v acc[4][4];
#pragma unroll
    for (int i = 0; i < 4; ++i)
#pragma unroll
        for (int j = 0; j < 4; ++j) acc[i][j] = 0.f;

    const int r0 = tid >> 2,        s0 = (tid & 3) * 8;
    const int r1 = (tid + 256) >> 2, s1 = ((tid + 256) & 3) * 8;

    for (int k0 = 0; k0 < K; k0 += 32) {
        *(s8v*)&As[r0][s0] = *(const s8v*)(Ab + (size_t)(m0 + r0) * lda + k0 + s0);
        *(s8v*)&As[r1][s1] = *(const s8v*)(Ab + (size_t)(m0 + r1) * lda + k0 + s1);
        *(s8v*)&Bs[r0][s0] = *(const s8v*)(Bb + (size_t)(n0 + r0) * ldb + k0 + s0);
        *(s8v*)&Bs[r1][s1] = *(const s8v*)(Bb + (size_t)(n0 + r1) * ldb + k0 + s1);
        __syncthreads();

        s8v af[4], bf[4];
#pragma unroll
        for (int i = 0; i < 4; ++i)
            af[i] = *(const s8v*)&As[wrow + i * 16 + l16][quad * 8];
#pragma unroll
        for (int j = 0; j < 4; ++j)
            bf[j] = *(const s8v*)&Bs[wcol + j * 16 + l16][quad * 8];
#pragma unroll
        for (int i = 0; i < 4; ++i)
#pragma unroll
            for (int j = 0; j < 4; ++j)
                acc[i][j] = __builtin_amdgcn_mfma_f32_16x16x32_bf16(
                    af[i], bf[j], acc[i][j], 0, 0, 0);
        __syncthreads();
    }

    float* Cf = (float*)C + (size_t)blockIdx.z * sC;
    __hip_bfloat16* Cb = (__hip_bfloat16*)C + (size_t)blockIdx.z * sC;
#pragma unroll
    for (int i = 0; i < 4; ++i)
#pragma unroll
        for (int j = 0; j < 4; ++j)
#pragma unroll
            for (int r = 0; r < 4; ++r) {
                const int m = m0 + wrow + i * 16 + quad * 4 + r;
                const int n = n0 + wcol + j * 16 + l16;
                float v = acc[i][j][r];
                if (bias)  v += bias[n];
                if (accum) v += Cf[(size_t)m * ldc + n];
                if (emul)  v *= emul[(size_t)m * ldmul + n];
                if (relu)  v = fmaxf(v, 0.f);
                if (out_bf16) Cb[(size_t)m * ldc + n] = __float2bfloat16(v);
                else          Cf[(size_t)m * ldc + n] = v;
            }
}

// ---------------------------------------------------------------------------
// M GEMM + fused softmax numerator (verified R13):
//   E = bf16(exp((a1d@a2^T)*W)); S[b][n] += column sums (fp32 atomics).
// ---------------------------------------------------------------------------
__global__ __launch_bounds__(256) void gemm_M(
    const __hip_bfloat16* __restrict__ A,   // a1db [32][512][256]
    const __hip_bfloat16* __restrict__ B,   // a2b  [32][512][256]
    __hip_bfloat16* __restrict__ E,         // Msb  [32][512][512]
    const float* __restrict__ Wm,           // [512,512]
    float* __restrict__ S)                  // [32][512] (pre-zeroed)
{
    __shared__ short As[128][40];
    __shared__ short Bs[128][40];

    const int tid  = threadIdx.x;
    const int wave = tid >> 6, lane = tid & 63;
    const int quad = lane >> 4, l16 = lane & 15;
    const int wrow = (wave >> 1) * 64, wcol = (wave & 1) * 64;
    const int m0 = blockIdx.y * 128, n0 = blockIdx.x * 128;

    const short* Ab = (const short*)A + (size_t)blockIdx.z * 131072;
    const short* Bb = (const short*)B + (size_t)blockIdx.z * 131072;

    f4v acc[4][4];
#pragma unroll
    for (int i = 0; i < 4; ++i)
#pragma unroll
        for (int j = 0; j < 4; ++j) acc[i][j] = 0.f;

    const int r0 = tid >> 2,        s0 = (tid & 3) * 8;
    const int r1 = (tid + 256) >> 2, s1 = ((tid + 256) & 3) * 8;

    for (int k0 = 0; k0 < 256; k0 += 32) {
        *(s8v*)&As[r0][s0] = *(const s8v*)(Ab + (size_t)(m0 + r0) * 256 + k0 + s0);
        *(s8v*)&As[r1][s1] = *(const s8v*)(Ab + (size_t)(m0 + r1) * 256 + k0 + s1);
        *(s8v*)&Bs[r0][s0] = *(const s8v*)(Bb + (size_t)(n0 + r0) * 256 + k0 + s0);
        *(s8v*)&Bs[r1][s1] = *(const s8v*)(Bb + (size_t)(n0 + r1) * 256 + k0 + s1);
        __syncthreads();

        s8v af[4], bf[4];
#pragma unroll
        for (int i = 0; i < 4; ++i)
            af[i] = *(const s8v*)&As[wrow + i * 16 + l16][quad * 8];
#pragma unroll
        for (int j = 0; j < 4; ++j)
            bf[j] = *(const s8v*)&Bs[wcol + j * 16 + l16][quad * 8];
#pragma unroll
        for (int i = 0; i < 4; ++i)
#pragma unroll
            for (int j = 0; j < 4; ++j)
                acc[i][j] = __builtin_amdgcn_mfma_f32_16x16x32_bf16(
                    af[i], bf[j], acc[i][j], 0, 0, 0);
        __syncthreads();
    }

    __hip_bfloat16* Eb = E + (size_t)blockIdx.z * 262144;
    float* Sb = S + blockIdx.z * 512;
#pragma unroll
    for (int j = 0; j < 4; ++j) {
        const int n = n0 + wcol + j * 16 + l16;
        float colsum = 0.f;
#pragma unroll
        for (int i = 0; i < 4; ++i)
#pragma unroll
            for (int r = 0; r < 4; ++r) {
                const int m = m0 + wrow + i * 16 + quad * 4 + r;
                float v = acc[i][j][r] * Wm[(size_t)m * 512 + n];
                float e = __expf(v);
                colsum += e;
                Eb[(size_t)m * 512 + n] = __float2bfloat16(e);
            }
        atomicAdd(&Sb[n], colsum);
    }
}

// Softmax denominator folded into x2tb (K-dim of the ctx GEMM):
//   x2tb[b][h][j] /= S[b][j].   ctx = Sum_j E[i,j] * (x2t[h,j]/S[j])
// is identical to normalizing E. 1/4 the traffic of scaling Msb.
__global__ __launch_bounds__(256) void sm_scale_x2(
    __hip_bfloat16* __restrict__ X, const float* __restrict__ S)
{
    const size_t t  = (size_t)blockIdx.x * 256 + threadIdx.x;  // 524288 threads
    const size_t e0 = t * 8;
    const int j0 = (int)(e0 & 511);
    const int b  = (int)(e0 >> 17);                            // 131072 per batch
    const float* Sb = S + b * 512 + j0;

    union { s8v v; __hip_bfloat16 h[8]; } u;
    u.v = *(const s8v*)(X + e0);
#pragma unroll
    for (int k = 0; k < 8; ++k)
        u.h[k] = __float2bfloat16(__bfloat162float(u.h[k]) / Sb[k]);
    *(s8v*)(X + e0) = u.v;
}

// ---------------------------------------------------------------------------
// Fused xp GEMM (verified R10): C = A1@B[:, :256]^T + A2@B[:, 256:]^T + bias.
// ---------------------------------------------------------------------------
__global__ __launch_bounds__(256) void gemm_xp(
    const __hip_bfloat16* __restrict__ A1,   // x1b  [16384,256]
    const __hip_bfloat16* __restrict__ A2,   // ctxb [16384,256]
    const __hip_bfloat16* __restrict__ B,    // wihb [768,512]
    float* __restrict__ C,                   // xp   [16384,768]
    const float* __restrict__ bias)          // bih  [768]
{
    __shared__ short As[128][40];
    __shared__ short Bs[128][40];

    const int tid  = threadIdx.x;
    const int wave = tid >> 6, lane = tid & 63;
    const int quad = lane >> 4, l16 = lane & 15;
    const int wrow = (wave >> 1) * 64, wcol = (wave & 1) * 64;
    const int m0 = blockIdx.y * 128, n0 = blockIdx.x * 128;

    f4v acc[4][4];
#pragma unroll
    for (int i = 0; i < 4; ++i)
#pragma unroll
        for (int j = 0; j < 4; ++j) acc[i][j] = 0.f;

    const int r0 = tid >> 2,        s0 = (tid & 3) * 8;
    const int r1 = (tid + 256) >> 2, s1 = ((tid + 256) & 3) * 8;

    for (int k0 = 0; k0 < 512; k0 += 32) {
        const short* Ab = (const short*)(k0 < 256 ? A1 : A2);
        const int ka = k0 & 255;
        *(s8v*)&As[r0][s0] = *(const s8v*)(Ab + (size_t)(m0 + r0) * 256 + ka + s0);
        *(s8v*)&As[r1][s1] = *(const s8v*)(Ab + (size_t)(m0 + r1) * 256 + ka + s1);
        *(s8v*)&Bs[r0][s0] = *(const s8v*)((const short*)B + (size_t)(n0 + r0) * 512 + k0 + s0);
        *(s8v*)&Bs[r1][s1] = *(const s8v*)((const short*)B + (size_t)(n0 + r1) * 512 + k0 + s1);
        __syncthreads();

        s8v af[4], bf[4];
#pragma unroll
        for (int i = 0; i < 4; ++i)
            af[i] = *(const s8v*)&As[wrow + i * 16 + l16][quad * 8];
#pragma unroll
        for (int j = 0; j < 4; ++j)
            bf[j] = *(const s8v*)&Bs[wcol + j * 16 + l16][quad * 8];
#pragma unroll
        for (int i = 0; i < 4; ++i)
#pragma unroll
            for (int j = 0; j < 4; ++j)
                acc[i][j] = __builtin_amdgcn_mfma_f32_16x16x32_bf16(
                    af[i], bf[j], acc[i][j], 0, 0, 0);
        __syncthreads();
    }

#pragma unroll
    for (int i = 0; i < 4; ++i)
#pragma unroll
        for (int j = 0; j < 4; ++j)
#pragma unroll
            for (int r = 0; r < 4; ++r) {
                const int m = m0 + wrow + i * 16 + quad * 4 + r;
                const int n = n0 + wcol + j * 16 + l16;
                C[(size_t)m * 768 + n] = acc[i][j][r] + bias[n];
            }
}

// fp32 -> bf16 elementwise (n % 4 == 0)
__global__ __launch_bounds__(256) void f2b(
    const float* __restrict__ s, __hip_bfloat16* __restrict__ d, int n)
{
    const int i = (blockIdx.x * 256 + threadIdx.x) * 4;
    if (i < n) {
        float4 v = *(const float4*)(s + i);
        d[i + 0] = __float2bfloat16(v.x);
        d[i + 1] = __float2bfloat16(v.y);
        d[i + 2] = __float2bfloat16(v.z);
        d[i + 3] = __float2bfloat16(v.w);
    }
}

// w1 + w2 casts merged + softmax-sum buffer S zeroed (runs pre-M-GEMM).
__global__ __launch_bounds__(256) void f2bw(
    const float* __restrict__ w1, const float* __restrict__ w2,
    __hip_bfloat16* __restrict__ w1b, __hip_bfloat16* __restrict__ w2b,
    float* __restrict__ S)
{
    const int gid = blockIdx.x * 256 + threadIdx.x;
    if (gid < 4096)
        *(float4*)(S + gid * 4) = make_float4(0.f, 0.f, 0.f, 0.f);
    const int i = gid * 4;
    const float* s;
    __hip_bfloat16* d;
    if (i < 65536) { s = w1 + i;           d = w1b + i; }
    else           { s = w2 + (i - 65536); d = w2b + (i - 65536); }
    float4 v = *(const float4*)s;
    d[0] = __float2bfloat16(v.x);
    d[1] = __float2bfloat16(v.y);
    d[2] = __float2bfloat16(v.z);
    d[3] = __float2bfloat16(v.w);
}

// fp32 [Z][R][C] -> bf16 [Z][C][R] tiled transpose
__global__ __launch_bounds__(256) void tr_f2b(
    const float* __restrict__ src, __hip_bfloat16* __restrict__ dst,
    int R, int C, long long sS, long long sD)
{
    __shared__ float t[32][33];
    const int r0 = blockIdx.y * 32, c0 = blockIdx.x * 32;
    const int tx = threadIdx.x & 31, ty = threadIdx.x >> 5;
    const float* S = src + (size_t)blockIdx.z * sS;
    __hip_bfloat16* Dd = dst + (size_t)blockIdx.z * sD;
#pragma unroll
    for (int i = 0; i < 32; i += 8)
        t[ty + i][tx] = S[(size_t)(r0 + ty + i) * C + c0 + tx];
    __syncthreads();
#pragma unroll
    for (int i = 0; i < 32; i += 8)
        Dd[(size_t)(c0 + ty + i) * R + r0 + tx] = __float2bfloat16(t[tx][ty + i]);
}

// Fused: x2 fp32 [Z][R][C] -> x2b bf16 same layout AND x2tb bf16 [Z][C][R].
__global__ __launch_bounds__(256) void f2b_tr(
    const float* __restrict__ src, __hip_bfloat16* __restrict__ dcast,
    __hip_bfloat16* __restrict__ dtr,
    int R, int C, long long sS, long long sD)
{
    __shared__ float t[32][33];
    const int r0 = blockIdx.y * 32, c0 = blockIdx.x * 32;
    const int tx = threadIdx.x & 31, ty = threadIdx.x >> 5;
    const float* S = src + (size_t)blockIdx.z * sS;
    __hip_bfloat16* Dc = dcast + (size_t)blockIdx.z * sS;
    __hip_bfloat16* Dd = dtr + (size_t)blockIdx.z * sD;
#pragma unroll
    for (int i = 0; i < 32; i += 8) {
        const size_t idx = (size_t)(r0 + ty + i) * C + c0 + tx;
        float v = S[idx];
        t[ty + i][tx] = v;
        Dc[idx] = __float2bfloat16(v);
    }
    __syncthreads();
#pragma unroll
    for (int i = 0; i < 32; i += 8)
        Dd[(size_t)(c0 + ty + i) * R + r0 + tx] = __float2bfloat16(t[tx][ty + i]);
}

// ---------------------------------------------------------------------------
// GRU (verified R11/R13, 658us): hp[768] = whh[768,256] @ h[256] via
// mfma_f32_16x16x32_f16. 512 threads = 8 waves; wave w owns output rows
// 96w..96w+95 (6 16-row tiles). Weight A-fragments in AGPRs. Per kk the wave
// reads ONE 16B B-fragment of h from LDS (fenced 1-deep pipeline).
//   A: lane->A[row=l16][k=quad*8+j]; B: lane->B[n=l16][k=quad*8+j]
//   D: lane->D[row=quad*4+r][col=l16]; all D columns equal hp.
// Gate phase: 256 threads, 1 h-element each. x(t+1) loads issued BEFORE the
// MFMA burst; consumed at the end of phase B (vmcnt covered by ~2000cyc).
// ---------------------------------------------------------------------------
__global__ __launch_bounds__(512, 2)
void gru_kernel(
    const float* __restrict__ xproj,   // [B, T, 768]
    const float* __restrict__ whh,     // [768, 256]
    const float* __restrict__ bhh,     // [768]
    float* __restrict__ out)           // [B, T, 256]
{
    const int b    = blockIdx.x;
    const int tid  = threadIdx.x;
    const int wave = tid >> 6, lane = tid & 63;
    const int quad = lane >> 4, l16 = lane & 15;

    __shared__ __align__(16) _Float16 hhf[256];   // h (f16), B operand
    __shared__ __align__(16) float    hp[768];    // whh @ h

    // --- Preload weight A-fragments: wreg[i][kk] = whh[96w+16i+l16][kk*32+quad*8 ..+7]
    h8v wreg[6][8];
#pragma unroll
    for (int i = 0; i < 6; ++i) {
        const float* rp = whh + (size_t)(96 * wave + 16 * i + l16) * 256 + quad * 8;
#pragma unroll
        for (int kk = 0; kk < 8; ++kk) {
            float4 t0 = *(const float4*)(rp + kk * 32);
            float4 t1 = *(const float4*)(rp + kk * 32 + 4);
            h8v f;
            f[0] = (_Float16)t0.x; f[1] = (_Float16)t0.y;
            f[2] = (_Float16)t0.z; f[3] = (_Float16)t0.w;
            f[4] = (_Float16)t1.x; f[5] = (_Float16)t1.y;
            f[6] = (_Float16)t1.z; f[7] = (_Float16)t1.w;
            wreg[i][kk] = f;
        }
    }

    const float* xb = xproj + (size_t)b * 512 * 768;
    float*       ob = out   + (size_t)b * 512 * 256;

    float hA = 0.f, xr = 0.f, xz = 0.f, xn = 0.f;
    float br = 0.f, bz = 0.f, bn = 0.f;
    if (tid < 256) {
        br = bhh[tid]; bz = bhh[256 + tid]; bn = bhh[512 + tid];
        xr = xb[tid];  xz = xb[256 + tid];  xn = xb[512 + tid];
        hhf[tid] = (_Float16)0.f;
    }
    bar_lds();

    for (int t = 0; t < 512; ++t) {
        // ---- x(t+1) prefetch: issue BEFORE the MFMA burst ------------------
        float nxr = 0.f, nxz = 0.f, nxn = 0.f;
        if (tid < 256) {
            const float* xpn = xb + (size_t)((t + 1) & 511) * 768;
            nxr = xpn[tid]; nxz = xpn[256 + tid]; nxn = xpn[512 + tid];
        }

        // ---- phase A: hp = whh @ h via MFMA --------------------------------
        f4v acc[6];
#pragma unroll
        for (int i = 0; i < 6; ++i) acc[i] = 0.f;

        h8v bf_cur = *(const h8v*)&hhf[quad * 8];
#pragma unroll
        for (int kk = 0; kk < 8; ++kk) {
            h8v bf_nxt = bf_cur;
            if (kk < 7) bf_nxt = *(const h8v*)&hhf[(kk + 1) * 32 + quad * 8];
#pragma unroll
            for (int i = 0; i < 6; ++i)
                acc[i] = __builtin_amdgcn_mfma_f32_16x16x32_f16(
                    wreg[i][kk], bf_cur, acc[i], 0, 0, 0);
            SCHED_FENCE();   // bound bf live range (VGPR budget), keep pipeline 1-deep
            bf_cur = bf_nxt;
        }

        if (l16 == 0) {      // lanes 0,16,32,48: rows 96w+16i+4q+{0..3}, col 0
#pragma unroll
            for (int i = 0; i < 6; ++i)
                *(f4v*)&hp[96 * wave + 16 * i + 4 * quad] = acc[i];
        }
        bar_lds();

        // ---- phase B: gates on 256 threads (1 h each) ----------------------
        if (tid < 256) {
            float hr = hp[tid]       + br;
            float hz = hp[256 + tid] + bz;
            float hn = hp[512 + tid] + bn;
            float r = fast_sig(xr + hr);
            float z = fast_sig(xz + hz);
            float n = fast_tanh(xn + r * hn);
            float h = (1.f - z) * n + z * hA;
            hA = h;
            hhf[tid] = (_Float16)h;
            ob[(size_t)t * 256 + tid] = h;
            xr = nxr; xz = nxz; xn = nxn;   // vmcnt wait lands here, covered
        }
        bar_lds();
    }
}

extern "C" void kernel_launch(void* const* d_in, const int* in_sizes, int n_in,
                              void* d_out, int out_size, void* d_ws, size_t ws_size,
                              hipStream_t stream)
{
    (void)in_sizes; (void)n_in; (void)out_size; (void)ws_size;

    const float* x1  = (const float*)d_in[0];   // [32,512,256]
    const float* x2  = (const float*)d_in[1];   // [32,512,256]
    const float* w1  = (const float*)d_in[2];   // [256,256]
    const float* w2  = (const float*)d_in[3];   // [256,256]
    const float* Dm  = (const float*)d_in[4];   // [256,256]
    const float* Wm  = (const float*)d_in[5];   // [512,512]
    const float* wih = (const float*)d_in[6];   // [768,512]
    const float* whh = (const float*)d_in[7];   // [768,256]
    const float* bih = (const float*)d_in[8];   // [768]
    const float* bhh = (const float*)d_in[9];   // [768]
    float* out = (float*)d_out;

    // Workspace aliasing (R13 base + a1db moved to +8MB).
    char* base = (char*)d_ws;
    __hip_bfloat16* w1b  = (__hip_bfloat16*)(base + 0);
    __hip_bfloat16* w2b  = (__hip_bfloat16*)(base + 131072);
    __hip_bfloat16* Dtb  = (__hip_bfloat16*)(base + 262144);
    float*          Ssum = (float*)(base + 1048576);        // [32*512] fp32
    float*          xp   = (float*)(base + 0);
    __hip_bfloat16* a1db = (__hip_bfloat16*)(base + 8388608);
    __hip_bfloat16* a1b  = (__hip_bfloat16*)(base + 33554432);
    __hip_bfloat16* Msb  = (__hip_bfloat16*)(base + 33554432);
    __hip_bfloat16* x1b  = (__hip_bfloat16*)(base + 50331648);
    __hip_bfloat16* x2b  = (__hip_bfloat16*)(base + 58720256);
    __hip_bfloat16* ctxb = (__hip_bfloat16*)(base + 58720256);
    __hip_bfloat16* x2tb = (__hip_bfloat16*)(base + 67108864);
    __hip_bfloat16* a2b  = (__hip_bfloat16*)(base + 75497472);
    __hip_bfloat16* wihb = (__hip_bfloat16*)(base + 75497472);

    dim3 blk(256);

    f2b<<<dim3(4096), blk, 0, stream>>>(x1, x1b, 4194304);
    f2b_tr<<<dim3(8, 16, 32), blk, 0, stream>>>(x2, x2b, x2tb, 512, 256, 131072, 131072);
    f2bw<<<dim3(128), blk, 0, stream>>>(w1, w2, w1b, w2b, Ssum);
    tr_f2b<<<dim3(8, 8, 1), blk, 0, stream>>>(Dm, Dtb, 256, 256, 0, 0);

    gemm_bf16<<<dim3(2, 128, 1), blk, 0, stream>>>(
        x1b, 256, 0, w1b, 256, 0, a1b, 256, 0, 256,
        nullptr, nullptr, 0, 1, 0, 1);
    gemm_bf16<<<dim3(2, 128, 1), blk, 0, stream>>>(
        x2b, 256, 0, w2b, 256, 0, a2b, 256, 0, 256,
        nullptr, nullptr, 0, 1, 0, 1);
    gemm_bf16<<<dim3(2, 128, 1), blk, 0, stream>>>(
        a1b, 256, 0, Dtb, 256, 0, a1db, 256, 0, 256,
        nullptr, nullptr, 0, 0, 0, 1);
    // M GEMM with fused exp + column-sum atomics: Msb = exp((a1d@a2^T)*W)
    gemm_M<<<dim3(4, 4, 32), blk, 0, stream>>>(a1db, a2b, Msb, Wm, Ssum);
    // wihb aliases a2b: cast only after gemm_M consumed a2b.
    f2b<<<dim3(384), blk, 0, stream>>>(wih, wihb, 393216);
    // softmax denominator folded into x2tb (K-dim scaling)
    sm_scale_x2<<<dim3(2048), blk, 0, stream>>>(x2tb, Ssum);
    gemm_bf16<<<dim3(2, 4, 32), blk, 0, stream>>>(
        Msb, 512, 262144, x2tb, 512, 131072, ctxb, 256, 131072, 512,
        nullptr, nullptr, 0, 0, 0, 1);
    // Fused xp = x1b @ wih[:, :256]^T + ctxb @ wih[:, 256:]^T + bih
    gemm_xp<<<dim3(6, 128, 1), blk, 0, stream>>>(x1b, ctxb, wihb, xp, bih);
    gru_kernel<<<dim3(32), dim3(512), 0, stream>>>(xp, whh, bhh, out);
}